// Round 3
// baseline (465.642 us; speedup 1.0000x reference)
//
#include <hip/hip_runtime.h>
#include <math.h>

#define BB 32
#define MM 2048
#define KK 4
#define EE 128
#define GG 128
#define VV 50000
#define HOPS 3
#define NBO 512      // o-GEMM partial blocks
#define CHUNK 98     // ceil(VV/NBO)

// ---------------- GRU cell: one block per batch row ----------------
__global__ __launch_bounds__(384) void gru_kernel(
    const float* __restrict__ emb0,   // emb table 0 [V][E]
    const int*   __restrict__ y,      // [B]
    const float* __restrict__ hprev,  // [B][G]
    const float* __restrict__ W_ih,   // [3G][E]
    const float* __restrict__ W_hh,   // [3G][G]
    const float* __restrict__ b_ih,   // [3G]
    const float* __restrict__ b_hh,   // [3G]
    float* __restrict__ h_out,        // d_out [B][G]
    float* __restrict__ q)            // ws    [B][G]
{
    int b = blockIdx.x;
    int t = threadIdx.x;
    __shared__ float x[EE], h[GG], gi[3*GG], gh[3*GG];
    if (t < EE)            x[t]       = emb0[(size_t)y[b]*EE + t];
    else if (t < 2*EE)     h[t-EE]    = hprev[b*GG + (t-EE)];
    __syncthreads();
    {
        float accI = b_ih[t], accH = b_hh[t];
        const float* wi = W_ih + (size_t)t*EE;
        const float* wh = W_hh + (size_t)t*GG;
        #pragma unroll 8
        for (int e = 0; e < EE; e++) { accI += x[e]*wi[e]; accH += h[e]*wh[e]; }
        gi[t] = accI; gh[t] = accH;
    }
    __syncthreads();
    if (t < GG) {
        float r = 1.f/(1.f + __expf(-(gi[t]        + gh[t])));
        float z = 1.f/(1.f + __expf(-(gi[GG+t]     + gh[GG+t])));
        float n = tanhf(gi[2*GG+t] + r*gh[2*GG+t]);
        float hn = (1.f - z)*n + z*h[t];
        h_out[b*GG + t] = hn;
        q[b*GG + t]     = hn;
    }
}

// ---------------- t[b][v] = emb_h[v] . q[b] : dense streaming GEMM ----------------
// Same structure as logits_kernel with K=128: 128 v-rows per block, 4v x 4b tile.
__global__ __launch_bounds__(256) void t_kernel(
    const float* __restrict__ q,      // [B][E]
    const float* __restrict__ embT,   // [V][E] A-table for this hop
    float* __restrict__ t)            // [B][V]
{
    __shared__ float Ut[EE][32];      // q transposed [e][b] (16 KB)
    __shared__ float Wt[32][132];     // [e_local][v_local], pad 128->132
    int tid = threadIdx.x;
    for (int i = tid; i < EE*32; i += 256) {
        int e = i >> 5, b = i & 31;
        Ut[e][b] = q[b*EE + e];
    }
    int vg = tid & 31;
    int bg = tid >> 5;
    int v0 = blockIdx.x * 128;
    float acc[4][4];
    #pragma unroll
    for (int i = 0; i < 4; i++)
        #pragma unroll
        for (int j = 0; j < 4; j++) acc[i][j] = 0.f;

    int vrow = tid >> 1;
    int half = tid & 1;
    const float* wrow = embT + (size_t)(v0 + vrow)*EE + half*16;
    bool vok = (v0 + vrow) < VV;

    for (int ec = 0; ec < EE; ec += 32) {
        __syncthreads();
        #pragma unroll
        for (int j = 0; j < 4; j++) {
            float4 w = make_float4(0.f, 0.f, 0.f, 0.f);
            if (vok) w = *(const float4*)(wrow + ec + j*4);
            int e0 = half*16 + j*4;
            Wt[e0+0][vrow] = w.x;
            Wt[e0+1][vrow] = w.y;
            Wt[e0+2][vrow] = w.z;
            Wt[e0+3][vrow] = w.w;
        }
        __syncthreads();
        #pragma unroll 8
        for (int e = 0; e < 32; e++) {
            float4 w = *(const float4*)(&Wt[e][vg*4]);
            float4 u = *(const float4*)(&Ut[ec + e][bg*4]);
            acc[0][0] += w.x*u.x; acc[0][1] += w.x*u.y; acc[0][2] += w.x*u.z; acc[0][3] += w.x*u.w;
            acc[1][0] += w.y*u.x; acc[1][1] += w.y*u.y; acc[1][2] += w.y*u.z; acc[1][3] += w.y*u.w;
            acc[2][0] += w.z*u.x; acc[2][1] += w.z*u.y; acc[2][2] += w.z*u.z; acc[2][3] += w.z*u.w;
            acc[3][0] += w.w*u.x; acc[3][1] += w.w*u.y; acc[3][2] += w.w*u.z; acc[3][3] += w.w*u.w;
        }
    }
    #pragma unroll
    for (int i = 0; i < 4; i++) {
        int v = v0 + vg*4 + i;
        if (v < VV) {
            #pragma unroll
            for (int j = 0; j < 4; j++)
                t[(size_t)(bg*4 + j)*VV + v] = acc[i][j];
        }
    }
}

// ---------------- fused scores + softmax + (scatter w | write attn) ----------------
// One block per batch row, 1024 threads, 2 slots/thread. Scores are 4B gathers from
// the L2-resident t[b] row (200 KB). Block owns w[b] exclusively: zero + scatter with
// no cross-block ordering. w[b][v] = sum of attn over all (m,k) with ctx==v.
template<int SCATTER>
__global__ __launch_bounds__(1024) void fssw_kernel(
    const float* __restrict__ t,      // [B][V]
    const int*   __restrict__ ctx,    // [B][M][K]
    float* __restrict__ w,            // [B][V]   (SCATTER)
    float* __restrict__ attn_out)     // [B][M]   (!SCATTER)
{
    int b   = blockIdx.x;
    int tid = threadIdx.x;
    const float* tb = t + (size_t)b*VV;
    float* wb = SCATTER ? (w + (size_t)b*VV) : (float*)0;
    if (SCATTER) {
        for (int i = tid; i < VV; i += 1024) wb[i] = 0.f;
    }
    int m1 = tid, m2 = tid + 1024;
    const int4 c1 = *(const int4*)(ctx + ((size_t)b*MM + m1)*KK);
    const int4 c2 = *(const int4*)(ctx + ((size_t)b*MM + m2)*KK);
    float s1 = tb[c1.x] + tb[c1.y] + tb[c1.z] + tb[c1.w];
    float s2 = tb[c2.x] + tb[c2.y] + tb[c2.z] + tb[c2.w];

    __shared__ float red[16];
    __shared__ float redm, reds;
    int wv = tid >> 6, lane = tid & 63;

    float mx = fmaxf(s1, s2);
    #pragma unroll
    for (int off = 32; off; off >>= 1) mx = fmaxf(mx, __shfl_down(mx, off));
    if (lane == 0) red[wv] = mx;
    __syncthreads();
    if (tid == 0) {
        float m = red[0];
        #pragma unroll
        for (int i = 1; i < 16; i++) m = fmaxf(m, red[i]);
        redm = m;
    }
    __syncthreads();
    mx = redm;
    float e1 = __expf(s1 - mx), e2 = __expf(s2 - mx);
    float sum = e1 + e2;
    #pragma unroll
    for (int off = 32; off; off >>= 1) sum += __shfl_down(sum, off);
    __syncthreads();
    if (lane == 0) red[wv] = sum;
    __syncthreads();
    if (tid == 0) {
        float s = 0.f;
        #pragma unroll
        for (int i = 0; i < 16; i++) s += red[i];
        reds = 1.f / s;
    }
    __syncthreads();
    float rs = reds;
    float a1 = e1 * rs, a2 = e2 * rs;
    if (SCATTER) {
        atomicAdd(&wb[c1.x], a1); atomicAdd(&wb[c1.y], a1);
        atomicAdd(&wb[c1.z], a1); atomicAdd(&wb[c1.w], a1);
        atomicAdd(&wb[c2.x], a2); atomicAdd(&wb[c2.y], a2);
        atomicAdd(&wb[c2.z], a2); atomicAdd(&wb[c2.w], a2);
    } else {
        attn_out[(size_t)b*MM + m1] = a1;
        attn_out[(size_t)b*MM + m2] = a2;
    }
}

// ---------------- o = w @ embC : dense streaming GEMM, partials over v-chunks ----------------
// Each block streams CHUNK table rows; w-chunk staged in LDS (broadcast reads).
__global__ __launch_bounds__(256) void ogemm_kernel(
    const float* __restrict__ embT,   // C-table [V][E]
    const float* __restrict__ w,      // [B][V]
    float* __restrict__ o_part)       // [NBO][32][128]
{
    __shared__ float ws[32][CHUNK];   // 12.5 KB
    int blk = blockIdx.x;
    int v0  = blk * CHUNK;
    int nrows = VV - v0; if (nrows > CHUNK) nrows = CHUNK; if (nrows < 0) nrows = 0;
    int tid = threadIdx.x;
    for (int i = tid; i < 32*CHUNK; i += 256) {
        int bb = i / CHUNK, r = i % CHUNK;
        ws[bb][r] = (r < nrows) ? w[(size_t)bb*VV + v0 + r] : 0.f;
    }
    __syncthreads();
    int e2 = tid & 63;                // e-pair
    int bg = tid >> 6;                // b-group of 8
    float2 a[8];
    #pragma unroll
    for (int j = 0; j < 8; j++) a[j] = make_float2(0.f, 0.f);
    #pragma unroll 2
    for (int r = 0; r < nrows; r++) {
        float2 ev = *(const float2*)(embT + (size_t)(v0 + r)*EE + e2*2);
        #pragma unroll
        for (int j = 0; j < 8; j++) {
            float wv = ws[bg*8 + j][r];
            a[j].x += wv * ev.x;
            a[j].y += wv * ev.y;
        }
    }
    #pragma unroll
    for (int j = 0; j < 8; j++)
        *(float2*)(o_part + ((size_t)blk*32 + bg*8 + j)*EE + e2*2) = a[j];
}

// ---------------- reduce partials, update q (and save o1 for hop 0) ----------------
template<int SAVE_O1>
__global__ __launch_bounds__(256) void ored_kernel(
    const float* __restrict__ o_part, // [NBO][4096]
    float* __restrict__ q,            // [B][E]
    float* __restrict__ o1)           // [B][E]
{
    int i = blockIdx.x*256 + threadIdx.x;   // 0..4095
    float s = 0.f;
    #pragma unroll 8
    for (int k = 0; k < NBO; k++) s += o_part[(size_t)k*4096 + i];
    q[i] += s;
    if (SAVE_O1) o1[i] = s;
}

// ---------------- vocab logits: 50000x32x256 GEMM, 4v x 4b register tile ----------------
__global__ __launch_bounds__(256) void logits_kernel(
    const float* __restrict__ h,      // [B][G]
    const float* __restrict__ o1,     // [B][E]
    const float* __restrict__ Wv,     // [V][256]
    const float* __restrict__ bv,     // [V]
    float* __restrict__ logits)       // [B][V]
{
    __shared__ float Ut[256][32];
    __shared__ float Wt[32][132];
    int t = threadIdx.x;
    for (int i = t; i < 256*32; i += 256) {
        int e = i >> 5, b = i & 31;
        Ut[e][b] = (e < GG) ? h[b*GG + e] : o1[b*EE + (e - GG)];
    }
    int vg = t & 31;
    int bg = t >> 5;
    int v0 = blockIdx.x * 128;
    float acc[4][4];
    #pragma unroll
    for (int i = 0; i < 4; i++)
        #pragma unroll
        for (int j = 0; j < 4; j++) acc[i][j] = 0.f;

    int vrow = t >> 1;
    int half = t & 1;
    const float* wrow = Wv + (size_t)(v0 + vrow)*256 + half*16;
    bool vok = (v0 + vrow) < VV;

    for (int ec = 0; ec < 256; ec += 32) {
        __syncthreads();
        #pragma unroll
        for (int j = 0; j < 4; j++) {
            float4 w = make_float4(0.f, 0.f, 0.f, 0.f);
            if (vok) w = *(const float4*)(wrow + ec + j*4);
            int e0 = half*16 + j*4;
            Wt[e0+0][vrow] = w.x;
            Wt[e0+1][vrow] = w.y;
            Wt[e0+2][vrow] = w.z;
            Wt[e0+3][vrow] = w.w;
        }
        __syncthreads();
        #pragma unroll 8
        for (int e = 0; e < 32; e++) {
            float4 w = *(const float4*)(&Wt[e][vg*4]);
            float4 u = *(const float4*)(&Ut[ec + e][bg*4]);
            acc[0][0] += w.x*u.x; acc[0][1] += w.x*u.y; acc[0][2] += w.x*u.z; acc[0][3] += w.x*u.w;
            acc[1][0] += w.y*u.x; acc[1][1] += w.y*u.y; acc[1][2] += w.y*u.z; acc[1][3] += w.y*u.w;
            acc[2][0] += w.z*u.x; acc[2][1] += w.z*u.y; acc[2][2] += w.z*u.z; acc[2][3] += w.z*u.w;
            acc[3][0] += w.w*u.x; acc[3][1] += w.w*u.y; acc[3][2] += w.w*u.z; acc[3][3] += w.w*u.w;
        }
    }
    #pragma unroll
    for (int i = 0; i < 4; i++) {
        int v = v0 + vg*4 + i;
        if (v < VV) {
            float bb = bv[v];
            #pragma unroll
            for (int j = 0; j < 4; j++)
                logits[(size_t)(bg*4 + j)*VV + v] = acc[i][j] + bb;
        }
    }
}

// ---------------- vocab softmax partial stats: 8 chunks per batch row ----------------
#define VCHUNK 6250
__global__ __launch_bounds__(256) void vpart_kernel(
    const float* __restrict__ logits, // [B][V]
    float* __restrict__ part)         // [B][8][2] = {max, sumexp}
{
    int blk = blockIdx.x;             // b*8 + c
    int b = blk >> 3, c = blk & 7;
    int t = threadIdx.x;
    const float* row = logits + (size_t)b*VV;
    int start = c*VCHUNK;
    int end   = min(start + VCHUNK, VV);
    __shared__ float red[4];
    int w = t >> 6, lane = t & 63;
    float mx = -INFINITY;
    for (int i = start + t; i < end; i += 256) mx = fmaxf(mx, row[i]);
    #pragma unroll
    for (int off = 32; off; off >>= 1) mx = fmaxf(mx, __shfl_down(mx, off));
    if (lane == 0) red[w] = mx;
    __syncthreads();
    float m = fmaxf(fmaxf(red[0], red[1]), fmaxf(red[2], red[3]));
    float sum = 0.f;
    for (int i = start + t; i < end; i += 256) sum += __expf(row[i] - m);
    #pragma unroll
    for (int off = 32; off; off >>= 1) sum += __shfl_down(sum, off);
    __syncthreads();
    if (lane == 0) red[w] = sum;
    __syncthreads();
    if (t == 0) {
        part[blk*2]   = m;
        part[blk*2+1] = red[0] + red[1] + red[2] + red[3];
    }
}

// ---------------- finalize p_vocab in place ----------------
__global__ __launch_bounds__(256) void vfinal_kernel(
    float* __restrict__ logits,       // [B][V], in-place
    const float* __restrict__ part)   // [B][8][2]
{
    int i = blockIdx.x*256 + threadIdx.x;
    if (i >= BB*VV) return;
    int b = i / VV;
    const float* pp = part + b*16;
    float M = -INFINITY;
    #pragma unroll
    for (int c = 0; c < 8; c++) M = fmaxf(M, pp[c*2]);
    float S = 0.f;
    #pragma unroll
    for (int c = 0; c < 8; c++) S += pp[c*2+1] * __expf(pp[c*2] - M);
    logits[i] = __expf(logits[i] - M) * (1.f / S);
}

extern "C" void kernel_launch(void* const* d_in, const int* in_sizes, int n_in,
                              void* d_out, int out_size, void* d_ws, size_t ws_size,
                              hipStream_t stream) {
    const int*   ctx    = (const int*)  d_in[0];
    const float* h_prev = (const float*)d_in[1];
    const int*   y      = (const int*)  d_in[2];
    const float* emb    = (const float*)d_in[3];
    const float* W_ih   = (const float*)d_in[4];
    const float* W_hh   = (const float*)d_in[5];
    const float* b_ih   = (const float*)d_in[6];
    const float* b_hh   = (const float*)d_in[7];
    const float* Wv     = (const float*)d_in[8];
    const float* bv     = (const float*)d_in[9];

    float* out_h    = (float*)d_out;                 // [B][G]
    float* out_pv   = out_h + BB*GG;                 // [B][V]
    float* out_attn = out_pv + (size_t)BB*VV;        // [B][M]

    float* ws     = (float*)d_ws;
    float* q      = ws;                         // 4096
    float* o1     = q + BB*EE;                  // 4096
    float* t      = o1 + BB*EE;                 // B*V = 1.6M floats
    float* w      = t + (size_t)BB*VV;          // B*V = 1.6M floats
    float* o_part = w + (size_t)BB*VV;          // NBO*4096 = 2.1M floats
    float* part   = o_part + (size_t)NBO*BB*EE; // 512

    const float* e0 = emb;
    const float* e1 = emb + (size_t)1*VV*EE;
    const float* e2 = emb + (size_t)2*VV*EE;

    // GRU -> h, q
    gru_kernel<<<BB, 384, 0, stream>>>(emb, y, h_prev, W_ih, W_hh, b_ih, b_hh, out_h, q);

    // hop 0: t0 = q.emb0^T (stream) ; scores+softmax+scatter ; o0 = w@emb1 (stream)
    t_kernel<<<391, 256, 0, stream>>>(q, e0, t);
    fssw_kernel<1><<<BB, 1024, 0, stream>>>(t, ctx, w, nullptr);
    ogemm_kernel<<<NBO, 256, 0, stream>>>(e1, w, o_part);
    ored_kernel<1><<<16, 256, 0, stream>>>(o_part, q, o1);   // q += o0, save o1

    // hop 1
    t_kernel<<<391, 256, 0, stream>>>(q, e1, t);
    fssw_kernel<1><<<BB, 1024, 0, stream>>>(t, ctx, w, nullptr);
    ogemm_kernel<<<NBO, 256, 0, stream>>>(e2, w, o_part);
    ored_kernel<0><<<16, 256, 0, stream>>>(o_part, q, nullptr);  // q += o1_hop

    // hop 2: only attn = softmax(scores) is observable (o/q dead in reference)
    t_kernel<<<391, 256, 0, stream>>>(q, e2, t);
    fssw_kernel<0><<<BB, 1024, 0, stream>>>(t, ctx, nullptr, out_attn);

    // vocab head
    logits_kernel<<<391, 256, 0, stream>>>(out_h, o1, Wv, bv, out_pv);
    vpart_kernel<<<BB*8, 256, 0, stream>>>(out_pv, part);
    vfinal_kernel<<<(BB*VV + 255)/256, 256, 0, stream>>>(out_pv, part);
}

// Round 4
// 338.967 us; speedup vs baseline: 1.3737x; 1.3737x over previous
//
#include <hip/hip_runtime.h>
#include <math.h>

#define BB 32
#define MM 2048
#define KK 4
#define EE 128
#define GG 128
#define VV 50000
#define HOPS 3

// ---------------- GRU cell: one block per batch row; also zeroes o1 ----------------
__global__ __launch_bounds__(384) void gru_kernel(
    const float* __restrict__ emb0,   // emb table 0 [V][E]
    const int*   __restrict__ y,      // [B]
    const float* __restrict__ hprev,  // [B][G]
    const float* __restrict__ W_ih,   // [3G][E]
    const float* __restrict__ W_hh,   // [3G][G]
    const float* __restrict__ b_ih,   // [3G]
    const float* __restrict__ b_hh,   // [3G]
    float* __restrict__ h_out,        // d_out [B][G]
    float* __restrict__ q,            // ws    [B][G]
    float* __restrict__ o1)           // ws    [B][E] -> zeroed (atomics later)
{
    int b = blockIdx.x;
    int t = threadIdx.x;
    __shared__ float x[EE], h[GG], gi[3*GG], gh[3*GG];
    if (t < EE)            x[t]       = emb0[(size_t)y[b]*EE + t];
    else if (t < 2*EE)     h[t-EE]    = hprev[b*GG + (t-EE)];
    if (t < EE) o1[b*EE + t] = 0.f;
    __syncthreads();
    {
        float accI = b_ih[t], accH = b_hh[t];
        const float* wi = W_ih + (size_t)t*EE;
        const float* wh = W_hh + (size_t)t*GG;
        #pragma unroll 8
        for (int e = 0; e < EE; e++) { accI += x[e]*wi[e]; accH += h[e]*wh[e]; }
        gi[t] = accI; gh[t] = accH;
    }
    __syncthreads();
    if (t < GG) {
        float r = 1.f/(1.f + __expf(-(gi[t]        + gh[t])));
        float z = 1.f/(1.f + __expf(-(gi[GG+t]     + gh[GG+t])));
        float n = tanhf(gi[2*GG+t] + r*gh[2*GG+t]);
        float hn = (1.f - z)*n + z*h[t];
        h_out[b*GG + t] = hn;
        q[b*GG + t]     = hn;
    }
}

// ---------------- t[b][v] = emb_h[v] . q[b] : dense streaming GEMM ----------------
// 128 v-rows per block, 4v x 4b register tile; table streamed coalesced once.
__global__ __launch_bounds__(256) void t_kernel(
    const float* __restrict__ q,      // [B][E]
    const float* __restrict__ embT,   // [V][E] A-table for this hop
    float* __restrict__ t)            // [B][V]
{
    __shared__ float Ut[EE][32];      // q transposed [e][b]
    __shared__ float Wt[32][132];     // [e_local][v_local], pad 128->132
    int tid = threadIdx.x;
    for (int i = tid; i < EE*32; i += 256) {
        int e = i >> 5, b = i & 31;
        Ut[e][b] = q[b*EE + e];
    }
    int vg = tid & 31;
    int bg = tid >> 5;
    int v0 = blockIdx.x * 128;
    float acc[4][4];
    #pragma unroll
    for (int i = 0; i < 4; i++)
        #pragma unroll
        for (int j = 0; j < 4; j++) acc[i][j] = 0.f;

    int vrow = tid >> 1;
    int half = tid & 1;
    const float* wrow = embT + (size_t)(v0 + vrow)*EE + half*16;
    bool vok = (v0 + vrow) < VV;

    for (int ec = 0; ec < EE; ec += 32) {
        __syncthreads();
        #pragma unroll
        for (int j = 0; j < 4; j++) {
            float4 w = make_float4(0.f, 0.f, 0.f, 0.f);
            if (vok) w = *(const float4*)(wrow + ec + j*4);
            int e0 = half*16 + j*4;
            Wt[e0+0][vrow] = w.x;
            Wt[e0+1][vrow] = w.y;
            Wt[e0+2][vrow] = w.z;
            Wt[e0+3][vrow] = w.w;
        }
        __syncthreads();
        #pragma unroll 8
        for (int e = 0; e < 32; e++) {
            float4 w = *(const float4*)(&Wt[e][vg*4]);
            float4 u = *(const float4*)(&Ut[ec + e][bg*4]);
            acc[0][0] += w.x*u.x; acc[0][1] += w.x*u.y; acc[0][2] += w.x*u.z; acc[0][3] += w.x*u.w;
            acc[1][0] += w.y*u.x; acc[1][1] += w.y*u.y; acc[1][2] += w.y*u.z; acc[1][3] += w.y*u.w;
            acc[2][0] += w.z*u.x; acc[2][1] += w.z*u.y; acc[2][2] += w.z*u.z; acc[2][3] += w.z*u.w;
            acc[3][0] += w.w*u.x; acc[3][1] += w.w*u.y; acc[3][2] += w.w*u.z; acc[3][3] += w.w*u.w;
        }
    }
    #pragma unroll
    for (int i = 0; i < 4; i++) {
        int v = v0 + vg*4 + i;
        if (v < VV) {
            #pragma unroll
            for (int j = 0; j < 4; j++)
                t[(size_t)(bg*4 + j)*VV + v] = acc[i][j];
        }
    }
}

// ---------------- scores via t-lookup: p[b][m] = sum_k t[b][ctx[b,m,k]] ----------------
__global__ __launch_bounds__(256) void scores_lookup_kernel(
    const float* __restrict__ t,      // [B][V]
    const int*   __restrict__ ctx,    // [B][M][K]
    float* __restrict__ p)            // [B][M]
{
    int gid = blockIdx.x*256 + threadIdx.x;   // == b*M + m
    int b   = gid >> 11;
    const int4 c = *(const int4*)(ctx + (size_t)gid*KK);
    const float* tb = t + (size_t)b*VV;
    p[gid] = tb[c.x] + tb[c.y] + tb[c.z] + tb[c.w];
}

// ---------------- fused: softmax stats + gathered weighted read + q update ----------------
// One block per (b, slot-chunk-of-64). Recomputes row softmax stats from p (8 KB),
// gathers the C-table rows for its 64 slots, atomically accumulates into q (and o1).
template<int SAVE_O1>
__global__ __launch_bounds__(256) void oacc_gather_kernel(
    const float* __restrict__ embT,   // emb + (hop+1)*V*E
    const int*   __restrict__ ctx,    // [B][M][K]
    const float* __restrict__ p,      // [B][M] raw scores
    float* __restrict__ q,            // [B][E] atomic +=
    float* __restrict__ o1)           // [B][E] atomic += (if SAVE_O1)
{
    int blk = blockIdx.x;             // b*32 + s
    int b = blk >> 5, s = blk & 31;
    int t = threadIdx.x;
    int w = t >> 6, lane = t & 63;

    // --- softmax stats over p[b][:] (all 2048) ---
    const float* row = p + (size_t)b*MM;
    float v[8];
    float mx = -INFINITY;
    #pragma unroll
    for (int i = 0; i < 8; i++) { v[i] = row[t + i*256]; mx = fmaxf(mx, v[i]); }
    __shared__ float red[6];
    #pragma unroll
    for (int off = 32; off; off >>= 1) mx = fmaxf(mx, __shfl_down(mx, off));
    if (lane == 0) red[w] = mx;
    __syncthreads();
    if (t == 0) red[4] = fmaxf(fmaxf(red[0],red[1]), fmaxf(red[2],red[3]));
    __syncthreads();
    mx = red[4];
    float sum = 0.f;
    #pragma unroll
    for (int i = 0; i < 8; i++) sum += __expf(v[i] - mx);
    #pragma unroll
    for (int off = 32; off; off >>= 1) sum += __shfl_down(sum, off);
    __syncthreads();
    if (lane == 0) red[w] = sum;
    __syncthreads();
    if (t == 0) red[5] = 1.f / (red[0]+red[1]+red[2]+red[3]);
    __syncthreads();
    float rs = red[5];

    // --- gather + weighted accumulate ---
    int m0 = s*64 + w*16;
    float ax = 0.f, ay = 0.f;
    for (int i = 0; i < 16; i++) {
        int m = m0 + i;
        float a = __expf(row[m] - mx) * rs;
        const int4 c = *(const int4*)(ctx + (size_t)(b*MM + m)*KK);
        float2 v0 = *(const float2*)(embT + (size_t)c.x*EE + lane*2);
        float2 v1 = *(const float2*)(embT + (size_t)c.y*EE + lane*2);
        float2 v2 = *(const float2*)(embT + (size_t)c.z*EE + lane*2);
        float2 v3 = *(const float2*)(embT + (size_t)c.w*EE + lane*2);
        ax += a * (v0.x + v1.x + v2.x + v3.x);
        ay += a * (v0.y + v1.y + v2.y + v3.y);
    }
    __shared__ float acc_red[4][EE];
    acc_red[w][lane*2]   = ax;
    acc_red[w][lane*2+1] = ay;
    __syncthreads();
    if (t < EE) {
        float vv = acc_red[0][t] + acc_red[1][t] + acc_red[2][t] + acc_red[3][t];
        atomicAdd(&q[b*EE + t], vv);
        if (SAVE_O1) atomicAdd(&o1[b*EE + t], vv);
    }
}

// ---------------- hop 2: fused t-lookup scores + softmax -> attn out ----------------
// One block per batch row, 1024 threads, 2 slots/thread; t row (200 KB) is L2/L3-hot.
__global__ __launch_bounds__(1024) void attn_fused_kernel(
    const float* __restrict__ t,      // [B][V]
    const int*   __restrict__ ctx,    // [B][M][K]
    float* __restrict__ attn_out)     // [B][M]
{
    int b   = blockIdx.x;
    int tid = threadIdx.x;
    const float* tb = t + (size_t)b*VV;
    int m1 = tid, m2 = tid + 1024;
    const int4 c1 = *(const int4*)(ctx + ((size_t)b*MM + m1)*KK);
    const int4 c2 = *(const int4*)(ctx + ((size_t)b*MM + m2)*KK);
    float s1 = tb[c1.x] + tb[c1.y] + tb[c1.z] + tb[c1.w];
    float s2 = tb[c2.x] + tb[c2.y] + tb[c2.z] + tb[c2.w];

    __shared__ float red[16];
    __shared__ float redm, reds;
    int wv = tid >> 6, lane = tid & 63;

    float mx = fmaxf(s1, s2);
    #pragma unroll
    for (int off = 32; off; off >>= 1) mx = fmaxf(mx, __shfl_down(mx, off));
    if (lane == 0) red[wv] = mx;
    __syncthreads();
    if (tid == 0) {
        float m = red[0];
        #pragma unroll
        for (int i = 1; i < 16; i++) m = fmaxf(m, red[i]);
        redm = m;
    }
    __syncthreads();
    mx = redm;
    float e1 = __expf(s1 - mx), e2 = __expf(s2 - mx);
    float sum = e1 + e2;
    #pragma unroll
    for (int off = 32; off; off >>= 1) sum += __shfl_down(sum, off);
    __syncthreads();
    if (lane == 0) red[wv] = sum;
    __syncthreads();
    if (tid == 0) {
        float s = 0.f;
        #pragma unroll
        for (int i = 0; i < 16; i++) s += red[i];
        reds = 1.f / s;
    }
    __syncthreads();
    float rs = reds;
    attn_out[(size_t)b*MM + m1] = e1 * rs;
    attn_out[(size_t)b*MM + m2] = e2 * rs;
}

// ---------------- vocab logits: 50000x32x256 GEMM, 4v x 4b register tile ----------------
__global__ __launch_bounds__(256) void logits_kernel(
    const float* __restrict__ h,      // [B][G]
    const float* __restrict__ o1,     // [B][E]
    const float* __restrict__ Wv,     // [V][256]
    const float* __restrict__ bv,     // [V]
    float* __restrict__ logits)       // [B][V]
{
    __shared__ float Ut[256][32];
    __shared__ float Wt[32][132];
    int t = threadIdx.x;
    for (int i = t; i < 256*32; i += 256) {
        int e = i >> 5, b = i & 31;
        Ut[e][b] = (e < GG) ? h[b*GG + e] : o1[b*EE + (e - GG)];
    }
    int vg = t & 31;
    int bg = t >> 5;
    int v0 = blockIdx.x * 128;
    float acc[4][4];
    #pragma unroll
    for (int i = 0; i < 4; i++)
        #pragma unroll
        for (int j = 0; j < 4; j++) acc[i][j] = 0.f;

    int vrow = t >> 1;
    int half = t & 1;
    const float* wrow = Wv + (size_t)(v0 + vrow)*256 + half*16;
    bool vok = (v0 + vrow) < VV;

    for (int ec = 0; ec < 256; ec += 32) {
        __syncthreads();
        #pragma unroll
        for (int j = 0; j < 4; j++) {
            float4 w = make_float4(0.f, 0.f, 0.f, 0.f);
            if (vok) w = *(const float4*)(wrow + ec + j*4);
            int e0 = half*16 + j*4;
            Wt[e0+0][vrow] = w.x;
            Wt[e0+1][vrow] = w.y;
            Wt[e0+2][vrow] = w.z;
            Wt[e0+3][vrow] = w.w;
        }
        __syncthreads();
        #pragma unroll 8
        for (int e = 0; e < 32; e++) {
            float4 w = *(const float4*)(&Wt[e][vg*4]);
            float4 u = *(const float4*)(&Ut[ec + e][bg*4]);
            acc[0][0] += w.x*u.x; acc[0][1] += w.x*u.y; acc[0][2] += w.x*u.z; acc[0][3] += w.x*u.w;
            acc[1][0] += w.y*u.x; acc[1][1] += w.y*u.y; acc[1][2] += w.y*u.z; acc[1][3] += w.y*u.w;
            acc[2][0] += w.z*u.x; acc[2][1] += w.z*u.y; acc[2][2] += w.z*u.z; acc[2][3] += w.z*u.w;
            acc[3][0] += w.w*u.x; acc[3][1] += w.w*u.y; acc[3][2] += w.w*u.z; acc[3][3] += w.w*u.w;
        }
    }
    #pragma unroll
    for (int i = 0; i < 4; i++) {
        int v = v0 + vg*4 + i;
        if (v < VV) {
            float bb = bv[v];
            #pragma unroll
            for (int j = 0; j < 4; j++)
                logits[(size_t)(bg*4 + j)*VV + v] = acc[i][j] + bb;
        }
    }
}

// ---------------- vocab softmax partial stats: 8 chunks per batch row ----------------
#define VCHUNK 6250
__global__ __launch_bounds__(256) void vpart_kernel(
    const float* __restrict__ logits, // [B][V]
    float* __restrict__ part)         // [B][8][2] = {max, sumexp}
{
    int blk = blockIdx.x;             // b*8 + c
    int b = blk >> 3, c = blk & 7;
    int t = threadIdx.x;
    const float* row = logits + (size_t)b*VV;
    int start = c*VCHUNK;
    int end   = min(start + VCHUNK, VV);
    __shared__ float red[4];
    int w = t >> 6, lane = t & 63;
    float mx = -INFINITY;
    for (int i = start + t; i < end; i += 256) mx = fmaxf(mx, row[i]);
    #pragma unroll
    for (int off = 32; off; off >>= 1) mx = fmaxf(mx, __shfl_down(mx, off));
    if (lane == 0) red[w] = mx;
    __syncthreads();
    float m = fmaxf(fmaxf(red[0], red[1]), fmaxf(red[2], red[3]));
    float sum = 0.f;
    for (int i = start + t; i < end; i += 256) sum += __expf(row[i] - m);
    #pragma unroll
    for (int off = 32; off; off >>= 1) sum += __shfl_down(sum, off);
    __syncthreads();
    if (lane == 0) red[w] = sum;
    __syncthreads();
    if (t == 0) {
        part[blk*2]   = m;
        part[blk*2+1] = red[0] + red[1] + red[2] + red[3];
    }
}

// ---------------- finalize p_vocab in place ----------------
__global__ __launch_bounds__(256) void vfinal_kernel(
    float* __restrict__ logits,       // [B][V], in-place
    const float* __restrict__ part)   // [B][8][2]
{
    int i = blockIdx.x*256 + threadIdx.x;
    if (i >= BB*VV) return;
    int b = i / VV;
    const float* pp = part + b*16;
    float M = -INFINITY;
    #pragma unroll
    for (int c = 0; c < 8; c++) M = fmaxf(M, pp[c*2]);
    float S = 0.f;
    #pragma unroll
    for (int c = 0; c < 8; c++) S += pp[c*2+1] * __expf(pp[c*2] - M);
    logits[i] = __expf(logits[i] - M) * (1.f / S);
}

extern "C" void kernel_launch(void* const* d_in, const int* in_sizes, int n_in,
                              void* d_out, int out_size, void* d_ws, size_t ws_size,
                              hipStream_t stream) {
    const int*   ctx    = (const int*)  d_in[0];
    const float* h_prev = (const float*)d_in[1];
    const int*   y      = (const int*)  d_in[2];
    const float* emb    = (const float*)d_in[3];
    const float* W_ih   = (const float*)d_in[4];
    const float* W_hh   = (const float*)d_in[5];
    const float* b_ih   = (const float*)d_in[6];
    const float* b_hh   = (const float*)d_in[7];
    const float* Wv     = (const float*)d_in[8];
    const float* bv     = (const float*)d_in[9];

    float* out_h    = (float*)d_out;                 // [B][G]
    float* out_pv   = out_h + BB*GG;                 // [B][V]
    float* out_attn = out_pv + (size_t)BB*VV;        // [B][M]

    float* ws   = (float*)d_ws;
    float* q    = ws;                       // 4096
    float* o1   = q + BB*EE;                // 4096
    float* p    = o1 + BB*EE;               // 65536
    float* t    = p + BB*MM;                // B*V = 1.6M floats (6.4 MB)
    float* part = t + (size_t)BB*VV;        // 512

    const float* e0 = emb;
    const float* e1 = emb + (size_t)1*VV*EE;
    const float* e2 = emb + (size_t)2*VV*EE;

    // GRU -> h, q ; zero o1
    gru_kernel<<<BB, 384, 0, stream>>>(emb, y, h_prev, W_ih, W_hh, b_ih, b_hh, out_h, q, o1);

    // hop 0: scores via table stream + L2 lookup; o via gather; q += o, save o1
    t_kernel<<<391, 256, 0, stream>>>(q, e0, t);
    scores_lookup_kernel<<<(BB*MM)/256, 256, 0, stream>>>(t, ctx, p);
    oacc_gather_kernel<1><<<BB*32, 256, 0, stream>>>(e1, ctx, p, q, o1);

    // hop 1
    t_kernel<<<391, 256, 0, stream>>>(q, e1, t);
    scores_lookup_kernel<<<(BB*MM)/256, 256, 0, stream>>>(t, ctx, p);
    oacc_gather_kernel<0><<<BB*32, 256, 0, stream>>>(e2, ctx, p, q, nullptr);

    // hop 2: only attn = softmax(scores) observable (o/q dead in reference)
    t_kernel<<<391, 256, 0, stream>>>(q, e2, t);
    attn_fused_kernel<<<BB, 1024, 0, stream>>>(t, ctx, out_attn);

    // vocab head
    logits_kernel<<<391, 256, 0, stream>>>(out_h, o1, Wv, bv, out_pv);
    vpart_kernel<<<BB*8, 256, 0, stream>>>(out_pv, part);
    vfinal_kernel<<<(BB*VV + 255)/256, 256, 0, stream>>>(out_pv, part);
}